// Round 3
// baseline (769.979 us; speedup 1.0000x reference)
//
#include <hip/hip_runtime.h>
#include <math.h>

#define FB 512
#define TB 256
#define PLANE (FB * TB)
typedef long long i64;
typedef _Float16 f16;
typedef _Float16 f16x8 __attribute__((ext_vector_type(8)));
typedef _Float16 f16x4 __attribute__((ext_vector_type(4)));
typedef float f32x4 __attribute__((ext_vector_type(4)));

#define MFMA16(a, b, c) __builtin_amdgcn_mfma_f32_16x16x32_f16(a, b, c, 0, 0, 0)

// ---------- Weff = W2 @ W1  (f32 accum, f16 out)
__global__ __launch_bounds__(256) void k_weff(const float* __restrict__ W1,
                                              const float* __restrict__ W2,
                                              f16* __restrict__ Weff) {
    const int m = blockIdx.y * 4 + (threadIdx.x >> 6);
    const int k = blockIdx.x * 64 + (threadIdx.x & 63);
    const float* w2r = W2 + (i64)m * FB;
    float acc = 0.f;
#pragma unroll 4
    for (int j = 0; j < FB; ++j) acc = fmaf(w2r[j], W1[(i64)j * FB + k], acc);
    Weff[(i64)m * FB + k] = (f16)acc;
}

// ---------- beff = W2 @ b1 + b2 (f32)
__global__ __launch_bounds__(256) void k_beff(const float* __restrict__ W2,
                                              const float* __restrict__ b1,
                                              const float* __restrict__ b2,
                                              float* __restrict__ beff) {
    const int m = blockIdx.x * 256 + threadIdx.x;
    const float* w2r = W2 + (i64)m * FB;
    float acc = b2[m];
#pragma unroll 4
    for (int k = 0; k < FB; ++k) acc = fmaf(w2r[k], b1[k], acc);
    beff[m] = acc;
}

// ---------- x f32 [f][t] -> xh f16 transposed [t][f], per plane, via LDS
__global__ __launch_bounds__(256) void k_transpose_cvt(const float* __restrict__ X,
                                                       f16* __restrict__ O) {
    __shared__ float ld[64][65];
    const int p = blockIdx.z;
    const float* src = X + (i64)p * PLANE;
    f16* dst = O + (i64)p * PLANE;
    const int f0 = blockIdx.y * 64, t0 = blockIdx.x * 64;
    const int tid = threadIdx.x;
    const int lrr = tid >> 4, lc = (tid & 15) * 4;
#pragma unroll
    for (int i = 0; i < 4; ++i) {
        float4 v = *(const float4*)&src[(i64)(f0 + lrr + i * 16) * TB + t0 + lc];
        ld[lrr + i * 16][lc + 0] = v.x;
        ld[lrr + i * 16][lc + 1] = v.y;
        ld[lrr + i * 16][lc + 2] = v.z;
        ld[lrr + i * 16][lc + 3] = v.w;
    }
    __syncthreads();
    const int tr = tid >> 2, fq = tid & 3;
#pragma unroll
    for (int i = 0; i < 4; ++i) {
        const int fl = fq * 16 + i * 4;
        f16x4 o;
#pragma unroll
        for (int j = 0; j < 4; ++j) o[j] = (f16)ld[fl + j][tr];
        *(f16x4*)&dst[(i64)(t0 + tr) * FB + f0 + fl] = o;
    }
}

// ---------- real MFMA GEMM: Out[t][m] (f16) = sum_k A[m][k]*In[t][k] + bias[m]
__global__ __launch_bounds__(256, 2) void k_rgemm(const f16* __restrict__ A,
                                                  const f16* __restrict__ In,
                                                  const float* __restrict__ bias,
                                                  f16* __restrict__ Out) {
    __shared__ f16 Asx[128][40], Bsx[128][40];
    const int slab = blockIdx.z;
    const f16* Bsrc = In + (i64)slab * PLANE;
    f16* Odst = Out + (i64)slab * PLANE;
    const int t0 = blockIdx.x * 128, m0 = blockIdx.y * 128;
    const int tid = threadIdx.x;
    const int wave = tid >> 6, lane = tid & 63;
    const int wm = wave >> 1, wn = wave & 1;
    const int lr = lane & 15, lg = lane >> 4;
    const int srow = tid >> 2, sgrp = (tid & 3) * 8;

    f32x4 acc[4][4] = {};
    f16x8 nA[2], nB[2];
#pragma unroll
    for (int i = 0; i < 2; ++i) {
        const int row = i * 64 + srow;
        nA[i] = *(const f16x8*)(A + (i64)(m0 + row) * FB + sgrp);
        nB[i] = *(const f16x8*)(Bsrc + (i64)(t0 + row) * FB + sgrp);
    }
#pragma unroll
    for (int i = 0; i < 2; ++i) {
        const int row = i * 64 + srow;
        *(f16x8*)&Asx[row][sgrp] = nA[i];
        *(f16x8*)&Bsx[row][sgrp] = nB[i];
    }
    __syncthreads();

#pragma unroll 1
    for (int kt = 0; kt < 16; ++kt) {
        if (kt < 15) {
            const int k0 = (kt + 1) * 32;
#pragma unroll
            for (int i = 0; i < 2; ++i) {
                const int row = i * 64 + srow;
                nA[i] = *(const f16x8*)(A + (i64)(m0 + row) * FB + k0 + sgrp);
                nB[i] = *(const f16x8*)(Bsrc + (i64)(t0 + row) * FB + k0 + sgrp);
            }
        }
        f16x8 aA[4], bB[4];
#pragma unroll
        for (int mf = 0; mf < 4; ++mf)
            aA[mf] = *(const f16x8*)&Asx[wm * 64 + mf * 16 + lr][lg * 8];
#pragma unroll
        for (int nf = 0; nf < 4; ++nf)
            bB[nf] = *(const f16x8*)&Bsx[wn * 64 + nf * 16 + lr][lg * 8];
#pragma unroll
        for (int nf = 0; nf < 4; ++nf)
#pragma unroll
            for (int mf = 0; mf < 4; ++mf)
                acc[mf][nf] = MFMA16(aA[mf], bB[nf], acc[mf][nf]);
        __syncthreads();
        if (kt < 15) {
#pragma unroll
            for (int i = 0; i < 2; ++i) {
                const int row = i * 64 + srow;
                *(f16x8*)&Asx[row][sgrp] = nA[i];
                *(f16x8*)&Bsx[row][sgrp] = nB[i];
            }
        }
        __syncthreads();
    }

#pragma unroll
    for (int mf = 0; mf < 4; ++mf) {
        const int m = m0 + wm * 64 + mf * 16 + lg * 4;
        const float4 bv = *(const float4*)&bias[m];
        const float bb[4] = {bv.x, bv.y, bv.z, bv.w};
#pragma unroll
        for (int nf = 0; nf < 4; ++nf) {
            const int t = t0 + wn * 64 + nf * 16 + lr;
            f16x4 o;
#pragma unroll
            for (int r = 0; r < 4; ++r) o[r] = (f16)(acc[mf][nf][r] + bb[r]);
            *(f16x4*)&Odst[(i64)t * FB + m] = o;
        }
    }
}

// ================= fused softmax + IDFT/mul/DFT (512-pt FFT per wave) ========
// Layout per sequence: position p = 8*lane + j (j = reg slot). DIF (sign +,
// conjDFT) leaves S[rev9(p)] at p; pointwise product in scrambled order; DIT
// (sign -) consumes rev order, emits natural. Twiddles via __sincosf.

__device__ __forceinline__ void bfly_dif(float& ar, float& ai, float& br, float& bi,
                                         float wc, float ws) {
    float dr = ar - br, di = ai - bi;
    ar = ar + br; ai = ai + bi;
    br = dr * wc - di * ws;
    bi = dr * ws + di * wc;
}
__device__ __forceinline__ void bfly_dit(float& ar, float& ai, float& br, float& bi,
                                         float wc, float ws) {
    float tr = br * wc - bi * ws;
    float ti = br * ws + bi * wc;
    br = ar - tr; bi = ai - ti;
    ar = ar + tr; ai = ai + ti;
}

#define TWO_PI_OVER_512 0.012271846303085129f

__device__ __forceinline__ void dif_cross(float re[8], float im[8], int m, int lane) {
    const int base = 8 * (lane & (m - 1));
    const int mul = 32 / m;
    const bool hi = (lane & m) != 0;
#pragma unroll
    for (int j = 0; j < 8; ++j) {
        float pr = __shfl_xor(re[j], m);
        float pi = __shfl_xor(im[j], m);
        float ar = hi ? pr : re[j], ai = hi ? pi : im[j];
        float br = hi ? re[j] : pr, bi = hi ? im[j] : pi;
        float th = TWO_PI_OVER_512 * (float)((base + j) * mul);
        float s, c;
        __sincosf(th, &s, &c);           // W+ = (c, +s)
        float dr = ar - br, di = ai - bi;
        float nr = dr * c - di * s;
        float ni = dr * s + di * c;
        re[j] = hi ? nr : ar + br;
        im[j] = hi ? ni : ai + bi;
    }
}

__device__ __forceinline__ void dit_cross(float re[8], float im[8], int m, int lane) {
    const int base = 8 * (lane & (m - 1));
    const int mul = 32 / m;
    const bool hi = (lane & m) != 0;
#pragma unroll
    for (int j = 0; j < 8; ++j) {
        float pr = __shfl_xor(re[j], m);
        float pi = __shfl_xor(im[j], m);
        float ar = hi ? pr : re[j], ai = hi ? pi : im[j];
        float br = hi ? re[j] : pr, bi = hi ? im[j] : pi;
        float th = TWO_PI_OVER_512 * (float)((base + j) * mul);
        float s, c;
        __sincosf(th, &s, &c);           // W- = (c, -s)
        float tbr = c * br + s * bi;
        float tbi = c * bi - s * br;
        re[j] = hi ? ar - tbr : ar + tbr;
        im[j] = hi ? ai - tbi : ai + tbi;
    }
}

#define R2C 0.70710678118654752f

__device__ __forceinline__ void fft_conj(float re[8], float im[8], int lane) { // F+ DIF
    dif_cross(re, im, 32, lane);
    dif_cross(re, im, 16, lane);
    dif_cross(re, im, 8, lane);
    dif_cross(re, im, 4, lane);
    dif_cross(re, im, 2, lane);
    dif_cross(re, im, 1, lane);
    // h=4 (W+ = e^{+i pi/4 * jlo})
    bfly_dif(re[0], im[0], re[4], im[4], 1.f, 0.f);
    bfly_dif(re[1], im[1], re[5], im[5], R2C, R2C);
    bfly_dif(re[2], im[2], re[6], im[6], 0.f, 1.f);
    bfly_dif(re[3], im[3], re[7], im[7], -R2C, R2C);
    // h=2
    bfly_dif(re[0], im[0], re[2], im[2], 1.f, 0.f);
    bfly_dif(re[1], im[1], re[3], im[3], 0.f, 1.f);
    bfly_dif(re[4], im[4], re[6], im[6], 1.f, 0.f);
    bfly_dif(re[5], im[5], re[7], im[7], 0.f, 1.f);
    // h=1
    bfly_dif(re[0], im[0], re[1], im[1], 1.f, 0.f);
    bfly_dif(re[2], im[2], re[3], im[3], 1.f, 0.f);
    bfly_dif(re[4], im[4], re[5], im[5], 1.f, 0.f);
    bfly_dif(re[6], im[6], re[7], im[7], 1.f, 0.f);
}

__device__ __forceinline__ void fft_fwd(float re[8], float im[8], int lane) { // F- DIT
    // h=1
    bfly_dit(re[0], im[0], re[1], im[1], 1.f, 0.f);
    bfly_dit(re[2], im[2], re[3], im[3], 1.f, 0.f);
    bfly_dit(re[4], im[4], re[5], im[5], 1.f, 0.f);
    bfly_dit(re[6], im[6], re[7], im[7], 1.f, 0.f);
    // h=2 (W- = e^{-i pi/2 * (jlo&1)})
    bfly_dit(re[0], im[0], re[2], im[2], 1.f, 0.f);
    bfly_dit(re[1], im[1], re[3], im[3], 0.f, -1.f);
    bfly_dit(re[4], im[4], re[6], im[6], 1.f, 0.f);
    bfly_dit(re[5], im[5], re[7], im[7], 0.f, -1.f);
    // h=4
    bfly_dit(re[0], im[0], re[4], im[4], 1.f, 0.f);
    bfly_dit(re[1], im[1], re[5], im[5], R2C, -R2C);
    bfly_dit(re[2], im[2], re[6], im[6], 0.f, -1.f);
    bfly_dit(re[3], im[3], re[7], im[7], -R2C, -R2C);
    dit_cross(re, im, 1, lane);
    dit_cross(re, im, 2, lane);
    dit_cross(re, im, 4, lane);
    dit_cross(re, im, 8, lane);
    dit_cross(re, im, 16, lane);
    dit_cross(re, im, 32, lane);
}

__device__ __forceinline__ float wave_max(float v) {
#pragma unroll
    for (int m = 1; m <= 32; m <<= 1) v = fmaxf(v, __shfl_xor(v, m));
    return v;
}
__device__ __forceinline__ float wave_sum(float v) {
#pragma unroll
    for (int m = 1; m <= 32; m <<= 1) v += __shfl_xor(v, m);
    return v;
}

// grid (32 t-blocks, 128 plane-pairs), block 256 (4 waves, 2 seqs each, 8 t/block)
__global__ __launch_bounds__(256, 4) void k_fftconv(const f16* __restrict__ xh,
                                                    const f16* __restrict__ logits,
                                                    float* __restrict__ out) {
    __shared__ float sR[8][520], sI[8][520];
    const int cs = blockIdx.y;
    const int b = cs >> 4, d = cs & 15;
    const int pre = b * 32 + d;
    const int pim = b * 32 + 16 + d;
    const int t0 = blockIdx.x * 8;
    const int tid = threadIdx.x;
    const int wave = tid >> 6, lane = tid & 63;

    // preload both sequences (latency hidden under first FFT chain)
    f16x8 Lhr[2], Lhi[2], Lwr[2], Lwi[2];
#pragma unroll
    for (int it = 0; it < 2; ++it) {
        const i64 row = (i64)(t0 + wave * 2 + it) * FB + lane * 8;
        Lhr[it] = *(const f16x8*)(xh + (i64)pre * PLANE + row);
        Lhi[it] = *(const f16x8*)(xh + (i64)pim * PLANE + row);
        Lwr[it] = *(const f16x8*)(logits + (i64)pre * PLANE + row);
        Lwi[it] = *(const f16x8*)(logits + (i64)pim * PLANE + row);
    }

#pragma unroll 1
    for (int it = 0; it < 2; ++it) {
        const int tl = wave * 2 + it;
        float hr[8], hi2[8], wr[8], wi[8];
#pragma unroll
        for (int j = 0; j < 8; ++j) {
            hr[j] = (float)Lhr[it][j];
            hi2[j] = (float)Lhi[it][j];
            wr[j] = (float)Lwr[it][j];
            wi[j] = (float)Lwi[it][j];
        }
        // softmax along f for each component plane
        {
            float mx = wr[0];
#pragma unroll
            for (int j = 1; j < 8; ++j) mx = fmaxf(mx, wr[j]);
            mx = wave_max(mx);
            float sm = 0.f;
#pragma unroll
            for (int j = 0; j < 8; ++j) { wr[j] = __expf(wr[j] - mx); sm += wr[j]; }
            sm = wave_sum(sm);
            const float inv = 1.0f / sm;
#pragma unroll
            for (int j = 0; j < 8; ++j) wr[j] *= inv;
        }
        {
            float mx = wi[0];
#pragma unroll
            for (int j = 1; j < 8; ++j) mx = fmaxf(mx, wi[j]);
            mx = wave_max(mx);
            float sm = 0.f;
#pragma unroll
            for (int j = 0; j < 8; ++j) { wi[j] = __expf(wi[j] - mx); sm += wi[j]; }
            sm = wave_sum(sm);
            const float inv = 1.0f / sm;
#pragma unroll
            for (int j = 0; j < 8; ++j) wi[j] *= inv;
        }
        // S1 = conjDFT(h), S2 = conjDFT(w)
        fft_conj(hr, hi2, lane);
        fft_conj(wr, wi, lane);
        // P = S1 * S2 / 512 (complex), scrambled order (consistent)
#pragma unroll
        for (int j = 0; j < 8; ++j) {
            const float pr = (hr[j] * wr[j] - hi2[j] * wi[j]) * (1.0f / 512.0f);
            const float pi = (hr[j] * wi[j] + hi2[j] * wr[j]) * (1.0f / 512.0f);
            wr[j] = pr; wi[j] = pi;
        }
        // out = DFT(P), natural order at p = 8*lane + j
        fft_fwd(wr, wi, lane);
        *(float4*)&sR[tl][8 * lane] = make_float4(wr[0], wr[1], wr[2], wr[3]);
        *(float4*)&sR[tl][8 * lane + 4] = make_float4(wr[4], wr[5], wr[6], wr[7]);
        *(float4*)&sI[tl][8 * lane] = make_float4(wi[0], wi[1], wi[2], wi[3]);
        *(float4*)&sI[tl][8 * lane + 4] = make_float4(wi[4], wi[5], wi[6], wi[7]);
    }
    __syncthreads();

    // cooperative coalesced write: f32 [f][t] planes
    float* Or = out + (i64)pre * PLANE;
    float* Oi = out + (i64)pim * PLANE;
    const int li = tid & 1, fi = tid >> 1;
#pragma unroll
    for (int w4 = 0; w4 < 4; ++w4) {
        const int f = fi + 128 * w4;
        float4 vr, vi;
        vr.x = sR[li * 4 + 0][f]; vr.y = sR[li * 4 + 1][f];
        vr.z = sR[li * 4 + 2][f]; vr.w = sR[li * 4 + 3][f];
        vi.x = sI[li * 4 + 0][f]; vi.y = sI[li * 4 + 1][f];
        vi.z = sI[li * 4 + 2][f]; vi.w = sI[li * 4 + 3][f];
        *(float4*)(Or + (i64)f * TB + t0 + li * 4) = vr;
        *(float4*)(Oi + (i64)f * TB + t0 + li * 4) = vi;
    }
}

extern "C" void kernel_launch(void* const* d_in, const int* in_sizes, int n_in,
                              void* d_out, int out_size, void* d_ws, size_t ws_size,
                              hipStream_t stream) {
    (void)in_sizes; (void)n_in; (void)out_size; (void)ws_size;
    const float* x = (const float*)d_in[0];
    const float* W1 = (const float*)d_in[1];
    const float* b1 = (const float*)d_in[2];
    const float* W2 = (const float*)d_in[3];
    const float* b2 = (const float*)d_in[4];
    float* out = (float*)d_out;

    char* ws = (char*)d_ws;
    f16* Weff = (f16*)(ws);                              // 512 KB
    float* beff = (float*)(ws + 524288);                 // 2 KB
    f16* xh = (f16*)(ws + 524288 + 4096);                // 67.1 MB
    f16* logits = (f16*)(ws + 524288 + 4096 + (i64)256 * PLANE * 2);

    // fused linear weights: Weff = W2@W1, beff = W2@b1 + b2
    k_weff<<<dim3(8, 128), dim3(256), 0, stream>>>(W1, W2, Weff);
    k_beff<<<dim3(2), dim3(256), 0, stream>>>(W2, b1, b2, beff);
    // x -> f16 [t][f]
    k_transpose_cvt<<<dim3(4, 8, 256), dim3(256), 0, stream>>>(x, xh);
    // logits = Weff @ X + beff (one fused linear pass)
    k_rgemm<<<dim3(TB / 128, FB / 128, 256), dim3(256), 0, stream>>>(Weff, xh, beff, logits);
    // fused softmax + IDFT -> pointwise mul -> DFT -> f32 [f][t]
    k_fftconv<<<dim3(32, 128), dim3(256), 0, stream>>>(xh, logits, out);
}